// Round 1
// baseline (603.860 us; speedup 1.0000x reference)
//
#include <hip/hip_runtime.h>

#define BB 256
#define TT 512
#define II 64
#define DD 512
#define OO 128
#define LN_EPS 1e-5f

__device__ __forceinline__ float fast_tanh(float x) {
    // tanh(x) = 1 - 2/(exp(2x)+1); exact saturation at +/-inf
    float e = __expf(2.0f * x);
    return 1.0f - 2.0f / (e + 1.0f);
}

__global__ __launch_bounds__(512, 2)
void fpm_kernel(const float* __restrict__ x,
                const float* __restrict__ W_in,
                const float* __restrict__ b_in,
                const float* __restrict__ gamma,
                const float* __restrict__ beta,
                const float* __restrict__ W_out,
                const float* __restrict__ b_out,
                const float* __restrict__ cs,
                float* __restrict__ out)
{
    const int b    = blockIdx.x;      // batch row
    const int tid  = threadIdx.x;     // 0..511 == d
    const int wave = tid >> 6;
    const int lane = tid & 63;

    __shared__ float red[2][8][2];    // [parity][wave][{sum, sumsq}]
    __shared__ float h_lds[DD];

    // --- stage W_in row d into registers (64 VGPRs) ---
    float w[II];
    const float4* Wrow = (const float4*)(W_in + tid * II);
    #pragma unroll
    for (int q = 0; q < II / 4; ++q) {
        float4 v = Wrow[q];
        w[4*q+0] = v.x; w[4*q+1] = v.y; w[4*q+2] = v.z; w[4*q+3] = v.w;
    }
    const float bi = b_in[tid];
    const float g  = gamma[tid];
    const float bt = beta[tid];
    const float scale = 1.0f / (1.0f + __expf(-cs[0]));

    const float* xrow = x + (size_t)b * TT * II;

    float s_prev = 0.0f, h_prev = 0.0f;

    for (int t = 0; t < TT; ++t) {
        const float* xt = xrow + t * II;   // block-uniform address -> s_load
        float a0 = 0.f, a1 = 0.f, a2 = 0.f, a3 = 0.f;
        #pragma unroll
        for (int i = 0; i < II; i += 4) {
            a0 = fmaf(xt[i+0], w[i+0], a0);
            a1 = fmaf(xt[i+1], w[i+1], a1);
            a2 = fmaf(xt[i+2], w[i+2], a2);
            a3 = fmaf(xt[i+3], w[i+3], a3);
        }
        float e = fast_tanh((a0 + a1) + (a2 + a3) + bi);
        float s = fast_tanh(e + scale * s_prev + h_prev);

        // --- block reduction for LayerNorm: sum(s), sum(s^2) ---
        float r0 = s, r1 = s * s;
        #pragma unroll
        for (int m = 32; m >= 1; m >>= 1) {
            r0 += __shfl_xor(r0, m, 64);
            r1 += __shfl_xor(r1, m, 64);
        }
        const int p = t & 1;
        if (lane == 0) { red[p][wave][0] = r0; red[p][wave][1] = r1; }
        __syncthreads();
        float sum = 0.f, sumsq = 0.f;
        #pragma unroll
        for (int wv = 0; wv < 8; ++wv) {
            sum   += red[p][wv][0];
            sumsq += red[p][wv][1];
        }
        const float mu   = sum * (1.0f / DD);
        const float var  = sumsq * (1.0f / DD) - mu * mu;
        const float rstd = rsqrtf(var + LN_EPS);
        const float h    = (s - mu) * rstd * g + bt;

        s_prev = s;
        h_prev = h;
    }

    // --- output GEMM: logits[b, o] = h . W_out[o, :] + b_out[o] ---
    h_lds[tid] = h_prev;
    __syncthreads();

    const int dbase = lane * 8;
    float hreg[8];
    #pragma unroll
    for (int k = 0; k < 8; ++k) hreg[k] = h_lds[dbase + k];

    for (int oo = 0; oo < 16; ++oo) {
        const int o = wave * 16 + oo;
        const float* wo = W_out + (size_t)o * DD + dbase;  // wave reads 2KB contiguous
        float pacc = 0.f;
        #pragma unroll
        for (int k = 0; k < 8; ++k) pacc = fmaf(wo[k], hreg[k], pacc);
        #pragma unroll
        for (int m = 32; m >= 1; m >>= 1) pacc += __shfl_xor(pacc, m, 64);
        if (lane == 0) out[(size_t)b * OO + o] = pacc + b_out[o];
    }
}

extern "C" void kernel_launch(void* const* d_in, const int* in_sizes, int n_in,
                              void* d_out, int out_size, void* d_ws, size_t ws_size,
                              hipStream_t stream) {
    const float* x      = (const float*)d_in[0];
    const float* W_in   = (const float*)d_in[1];
    const float* b_in   = (const float*)d_in[2];
    const float* gamma  = (const float*)d_in[3];
    const float* beta   = (const float*)d_in[4];
    const float* W_out  = (const float*)d_in[5];
    const float* b_out  = (const float*)d_in[6];
    const float* cs     = (const float*)d_in[7];
    float* out = (float*)d_out;

    fpm_kernel<<<BB, 512, 0, stream>>>(x, W_in, b_in, gamma, beta, W_out, b_out, cs, out);
}